// Round 4
// baseline (20211.916 us; speedup 1.0000x reference)
//
#include <hip/hip_runtime.h>
#include <hip/hip_fp16.h>
#include <hip/hip_cooperative_groups.h>
#include <math.h>

namespace cg = cooperative_groups;

#define B 64
#define L 128
#define N_ 512
#define E_ 512
#define H_ 512
#define G3 1536
#define NEG -1e9f

__device__ __forceinline__ float2 uh2f2(unsigned u) {
  __half2 h;
  __builtin_memcpy(&h, &u, 4);
  return __half22float2(h);
}
__device__ __forceinline__ unsigned f2uh2(float x, float y) {
  __half2 h = __floats2half2_rn(x, y);
  unsigned u;
  __builtin_memcpy(&u, &h, 4);
  return u;
}

// ---------------- precompute kernels (once per call) ----------------

__global__ __launch_bounds__(512) void k_init(const float* __restrict__ state,
                                              float* __restrict__ h32,
                                              unsigned* __restrict__ h2g,
                                              float* __restrict__ cov,
                                              unsigned* __restrict__ scnt) {
  int i = blockIdx.x * 512 + threadIdx.x;  // 0..32767
  int jh = i >> 6, b = i & 63;
  float v = state[b * H_ + jh];
  h32[i] = v;
  ((__half*)h2g)[((size_t)(jh >> 1) * 64 + b) * 2 + (jh & 1)] = __float2half(v);
  cov[i] = 0.f;
  if (i < 64) scnt[i] = 0u;
}

__global__ __launch_bounds__(256) void k_cvt(const float* __restrict__ v,
                                             __half* __restrict__ o) {
  size_t i = ((size_t)blockIdx.x * 256 + threadIdx.x) * 4;
  float4 f = *(const float4*)(v + i);
  __half2* d = (__half2*)(o + i);
  d[0] = __floats2half2_rn(f.x, f.y);
  d[1] = __floats2half2_rn(f.z, f.w);
}

// vk[b,n,k] = sum_h value[b,n,h]*Wk[k,h] + b_attn[k]   (fp16)
__global__ __launch_bounds__(256) void k_vk(const float* __restrict__ value,
                                            const float* __restrict__ Wk,
                                            const float* __restrict__ b_attn,
                                            __half* __restrict__ vk) {
  int k0 = blockIdx.x * 64, n0 = blockIdx.y * 64, b = blockIdx.z;
  int tid = threadIdx.x;
  int tn = tid >> 4, tk = tid & 15;
  __shared__ float Vs[64][33];
  __shared__ float Ws[64][33];
  const float* vb = value + (size_t)b * N_ * H_;
  float acc[4][4] = {};
  for (int h0 = 0; h0 < H_; h0 += 32) {
#pragma unroll
    for (int e = 0; e < 8; ++e) {
      int idx = tid + e * 256;
      int r = idx >> 5, c = idx & 31;
      Vs[r][c] = vb[(size_t)(n0 + r) * H_ + h0 + c];
      Ws[r][c] = Wk[(size_t)(k0 + r) * H_ + h0 + c];
    }
    __syncthreads();
#pragma unroll
    for (int c = 0; c < 32; ++c) {
      float av[4], wv[4];
#pragma unroll
      for (int i = 0; i < 4; ++i) av[i] = Vs[tn * 4 + i][c];
#pragma unroll
      for (int jq = 0; jq < 4; ++jq) wv[jq] = Ws[tk * 4 + jq][c];
#pragma unroll
      for (int i = 0; i < 4; ++i)
#pragma unroll
        for (int jq = 0; jq < 4; ++jq) acc[i][jq] += av[i] * wv[jq];
    }
    __syncthreads();
  }
  __half* vkb = vk + (size_t)b * N_ * H_;
  float4 bav = *(const float4*)(b_attn + k0 + tk * 4);
#pragma unroll
  for (int i = 0; i < 4; ++i) {
    __half2 lo = __floats2half2_rn(acc[i][0] + bav.x, acc[i][1] + bav.y);
    __half2 hi = __floats2half2_rn(acc[i][2] + bav.z, acc[i][3] + bav.w);
    __half2* dst = (__half2*)&vkb[(size_t)(n0 + tn * 4 + i) * H_ + k0 + tk * 4];
    dst[0] = lo;
    dst[1] = hi;
  }
}

// gi_e[t, col, b] = emb[b,t,:]@W_ih[col,:E] + b_ih[col]  (fp16, b fastest)
__global__ __launch_bounds__(256) void k_gie(const float* __restrict__ emb,
                                             const float* __restrict__ W_ih,
                                             const float* __restrict__ b_ih,
                                             __half* __restrict__ gie) {
  int c0 = blockIdx.x * 64;
  int t = blockIdx.y;
  int tid = threadIdx.x;
  int tn = tid >> 4, tk = tid & 15;
  __shared__ float As[64][33];
  __shared__ float Ws[64][33];
  float acc[4][4] = {};
  for (int h0 = 0; h0 < E_; h0 += 32) {
#pragma unroll
    for (int e = 0; e < 8; ++e) {
      int idx = tid + e * 256;
      int r = idx >> 5, c = idx & 31;
      As[r][c] = emb[((size_t)r * L + t) * E_ + h0 + c];
      Ws[r][c] = W_ih[(size_t)(c0 + r) * (E_ + H_) + h0 + c];
    }
    __syncthreads();
#pragma unroll
    for (int c = 0; c < 32; ++c) {
      float av[4], wv[4];
#pragma unroll
      for (int i = 0; i < 4; ++i) av[i] = As[tn * 4 + i][c];
#pragma unroll
      for (int jq = 0; jq < 4; ++jq) wv[jq] = Ws[tk * 4 + jq][c];
#pragma unroll
      for (int i = 0; i < 4; ++i)
#pragma unroll
        for (int jq = 0; jq < 4; ++jq) acc[i][jq] += av[i] * wv[jq];
    }
    __syncthreads();
  }
#pragma unroll
  for (int jq = 0; jq < 4; ++jq) {
    int col = c0 + tk * 4 + jq;
    float bi = b_ih[col];
    __half2 lo = __floats2half2_rn(acc[0][jq] + bi, acc[1][jq] + bi);
    __half2 hi = __floats2half2_rn(acc[2][jq] + bi, acc[3][jq] + bi);
    __half2* dst = (__half2*)(gie + ((size_t)t * G3 + col) * 64 + tn * 4);
    dst[0] = lo;
    dst[1] = hi;
  }
}

// ---------------- the persistent decoder ----------------

__global__ __launch_bounds__(512, 1) void k_step(
    const __half* __restrict__ vk, const __half* __restrict__ val_h,
    const __half* __restrict__ gie, const float* __restrict__ Wq,
    const float* __restrict__ Whh, const float* __restrict__ Wih,
    const float* __restrict__ b_hh, const float* __restrict__ w_cov,
    const float* __restrict__ v_attn, const float* __restrict__ vmask,
    float* __restrict__ cov, float* __restrict__ h32,
    unsigned* __restrict__ h2g, float* __restrict__ out1,
    float* __restrict__ scores, unsigned* __restrict__ ctx2,
    unsigned* __restrict__ scnt, float* __restrict__ out_h,
    float* __restrict__ attn_out) {
  cg::grid_group gg = cg::this_grid();
  const int bx = blockIdx.x;    // 0..255
  const int tid = threadIdx.x;  // 0..511
  const int lane = tid & 63;
  const int wv = __builtin_amdgcn_readfirstlane(tid >> 6);  // 0..7

  __shared__ unsigned sh_h2[16384];      // 64 KB: A: h fp16 [k2][b] | C: ctx
  __shared__ float sh_part[8][2][64];    // A partials
  __shared__ float sh_part6[6][8][64];   // C partials
  __shared__ float sh_qs[512];
  __shared__ float sh_covs[256];
  __shared__ float sh_sc[256];
  __shared__ float sh_at[512];
  __shared__ float sh_red[8], sh_red2[8];
  __shared__ float sh_cpart[4][128][2];

  // ---- hoisted per-lane constants (attention) ----
  const int bq = bx >> 1, hh = bx & 1;  // valid when bx < 128
  float wc8[8], va8[8], mymask = 0.f;
  if (bx < 128) {
    float4 a0 = *(const float4*)(w_cov + lane * 8);
    float4 a1 = *(const float4*)(w_cov + lane * 8 + 4);
    wc8[0] = a0.x; wc8[1] = a0.y; wc8[2] = a0.z; wc8[3] = a0.w;
    wc8[4] = a1.x; wc8[5] = a1.y; wc8[6] = a1.z; wc8[7] = a1.w;
    float4 b0 = *(const float4*)(v_attn + lane * 8);
    float4 b1 = *(const float4*)(v_attn + lane * 8 + 4);
    va8[0] = b0.x; va8[1] = b0.y; va8[2] = b0.z; va8[3] = b0.w;
    va8[4] = b1.x; va8[5] = b1.y; va8[6] = b1.z; va8[7] = b1.w;
    if (tid < 256) mymask = vmask[bq * N_ + hh * 256 + tid];
  }

  for (int t = 0; t < L; ++t) {
    // ================= Phase A: out1[col][b] = [q | gh] =================
#pragma unroll
    for (int e = 0; e < 32; ++e) {
      int idx = tid + e * 512;
      sh_h2[idx] = h2g[idx];
    }
    __syncthreads();
    {
      int pairI = wv & 3, kh = wv >> 2;
      int c0 = __builtin_amdgcn_readfirstlane(bx * 8 + pairI * 2);
      const float* w0p = (c0 < 512) ? (Wq + (size_t)c0 * 512)
                                    : (Whh + (size_t)(c0 - 512) * 512);
      const float* w1p = w0p + 512;
      float a0 = 0.f, a1 = 0.f;
      int base = kh * 128;
#pragma unroll 8
      for (int k2 = 0; k2 < 128; ++k2) {
        float2 hf = uh2f2(sh_h2[(base + k2) * 64 + lane]);
        float2 wa = *(const float2*)(w0p + (base + k2) * 2);
        float2 wb = *(const float2*)(w1p + (base + k2) * 2);
        a0 = fmaf(hf.x, wa.x, a0); a0 = fmaf(hf.y, wa.y, a0);
        a1 = fmaf(hf.x, wb.x, a1); a1 = fmaf(hf.y, wb.y, a1);
      }
      sh_part[pairI * 2 + 0][kh][lane] = a0;
      sh_part[pairI * 2 + 1][kh][lane] = a1;
    }
    __syncthreads();
    {
      int colIdx = tid >> 6;
      int col = bx * 8 + colIdx;
      float acc = sh_part[colIdx][0][lane] + sh_part[colIdx][1][lane];
      if (col >= 512) acc += b_hh[col - 512];
      out1[(size_t)col * 64 + lane] = acc;
    }
    gg.sync();  // ---- sync1: out1 ready ----

    // ================= Phase B: attention (WGs 0..127) =================
    if (bx < 128) {
      sh_qs[tid] = out1[(size_t)tid * 64 + bq];
      if (tid < 256) sh_covs[tid] = cov[bq * N_ + hh * 256 + tid];
      __syncthreads();
      float q8[8];
#pragma unroll
      for (int k = 0; k < 8; ++k) q8[k] = sh_qs[lane * 8 + k];

      const __half2* vkb =
          (const __half2*)vk + ((size_t)bq * N_ + hh * 256) * 256;
      for (int r = 0; r < 32; ++r) {
        int nl = wv * 32 + r;
        float cv = sh_covs[nl];
        float4 raw = *(const float4*)(vkb + (size_t)nl * 256 + lane * 4);
        const __half2* hp = (const __half2*)&raw;
        float p = 0.f;
#pragma unroll
        for (int k = 0; k < 4; ++k) {
          float2 f = __half22float2(hp[k]);
          float e0 = fmaf(cv, wc8[2 * k], q8[2 * k]) + f.x;
          float e1 = fmaf(cv, wc8[2 * k + 1], q8[2 * k + 1]) + f.y;
          p = fmaf(fmaxf(e0, 0.f), va8[2 * k], p);
          p = fmaf(fmaxf(e1, 0.f), va8[2 * k + 1], p);
        }
#pragma unroll
        for (int off = 32; off; off >>= 1) p += __shfl_xor(p, off);
        if (lane == 0) sh_sc[nl] = p;
      }
      __syncthreads();
      if (tid < 256)
        scores[bq * N_ + hh * 256 + tid] = (mymask > 0.f) ? sh_sc[tid] : NEG;
      __syncthreads();
      if (tid == 0) {
        __hip_atomic_fetch_add(&scnt[bq], 1u, __ATOMIC_RELEASE,
                               __HIP_MEMORY_SCOPE_AGENT);
        unsigned target = 2u * (unsigned)(t + 1);
        while (__hip_atomic_load(&scnt[bq], __ATOMIC_ACQUIRE,
                                 __HIP_MEMORY_SCOPE_AGENT) < target) {
          __builtin_amdgcn_s_sleep(1);
        }
      }
      __syncthreads();

      // full softmax (redundant in both pair WGs)
      float sv = scores[bq * N_ + tid];
      float m = sv;
#pragma unroll
      for (int off = 32; off; off >>= 1) m = fmaxf(m, __shfl_xor(m, off));
      if (lane == 0) sh_red[wv] = m;
      __syncthreads();
      m = sh_red[0];
#pragma unroll
      for (int k = 1; k < 8; ++k) m = fmaxf(m, sh_red[k]);
      float p = expf(sv - m);
      float s = p;
#pragma unroll
      for (int off = 32; off; off >>= 1) s += __shfl_xor(s, off);
      if (lane == 0) sh_red2[wv] = s;
      __syncthreads();
      s = 0.f;
#pragma unroll
      for (int k = 0; k < 8; ++k) s += sh_red2[k];
      float a = p * (1.f / s);
      sh_at[tid] = a;
      if ((tid >> 8) == hh) {
        cov[bq * N_ + tid] += a;
        attn_out[((size_t)bq * L + t) * N_ + tid] = a;
      }
      __syncthreads();

      // context for this WG's h-half
      int part = tid >> 7, h2i = tid & 127;
      const __half2* vb =
          (const __half2*)val_h + (size_t)bq * N_ * 256 + hh * 128 + h2i;
      float cx = 0.f, cy = 0.f;
      for (int n = part * 128; n < part * 128 + 128; ++n) {
        float av = sh_at[n];
        float2 f = __half22float2(vb[(size_t)n * 256]);
        cx = fmaf(av, f.x, cx);
        cy = fmaf(av, f.y, cy);
      }
      sh_cpart[part][h2i][0] = cx;
      sh_cpart[part][h2i][1] = cy;
      __syncthreads();
      if (tid < 128) {
        float sx = sh_cpart[0][tid][0] + sh_cpart[1][tid][0] +
                   sh_cpart[2][tid][0] + sh_cpart[3][tid][0];
        float sy = sh_cpart[0][tid][1] + sh_cpart[1][tid][1] +
                   sh_cpart[2][tid][1] + sh_cpart[3][tid][1];
        ctx2[(size_t)(hh * 128 + tid) * 64 + bq] = f2uh2(sx, sy);
      }
    }
    gg.sync();  // ---- sync2: ctx2 ready ----

    // ================= Phase C: gc GEMV + GRU pointwise =================
#pragma unroll
    for (int e = 0; e < 32; ++e) {
      int idx = tid + e * 512;
      sh_h2[idx] = ctx2[idx];
    }
    __syncthreads();
    {
      int jh0 = bx * 2;
      int kb = wv * 32;
      float acc[6] = {0.f, 0.f, 0.f, 0.f, 0.f, 0.f};
      const float* wrow0 = Wih + (size_t)(jh0) * 1024 + 512;
      const float* wrow1 = Wih + (size_t)(jh0 + 1) * 1024 + 512;
      const float* wrow2 = Wih + (size_t)(512 + jh0) * 1024 + 512;
      const float* wrow3 = Wih + (size_t)(512 + jh0 + 1) * 1024 + 512;
      const float* wrow4 = Wih + (size_t)(1024 + jh0) * 1024 + 512;
      const float* wrow5 = Wih + (size_t)(1024 + jh0 + 1) * 1024 + 512;
#pragma unroll 4
      for (int k2 = kb; k2 < kb + 32; ++k2) {
        float2 cf = uh2f2(sh_h2[k2 * 64 + lane]);
        float2 w0 = *(const float2*)(wrow0 + k2 * 2);
        float2 w1 = *(const float2*)(wrow1 + k2 * 2);
        float2 w2 = *(const float2*)(wrow2 + k2 * 2);
        float2 w3 = *(const float2*)(wrow3 + k2 * 2);
        float2 w4 = *(const float2*)(wrow4 + k2 * 2);
        float2 w5 = *(const float2*)(wrow5 + k2 * 2);
        acc[0] = fmaf(cf.x, w0.x, acc[0]); acc[0] = fmaf(cf.y, w0.y, acc[0]);
        acc[1] = fmaf(cf.x, w1.x, acc[1]); acc[1] = fmaf(cf.y, w1.y, acc[1]);
        acc[2] = fmaf(cf.x, w2.x, acc[2]); acc[2] = fmaf(cf.y, w2.y, acc[2]);
        acc[3] = fmaf(cf.x, w3.x, acc[3]); acc[3] = fmaf(cf.y, w3.y, acc[3]);
        acc[4] = fmaf(cf.x, w4.x, acc[4]); acc[4] = fmaf(cf.y, w4.y, acc[4]);
        acc[5] = fmaf(cf.x, w5.x, acc[5]); acc[5] = fmaf(cf.y, w5.y, acc[5]);
      }
#pragma unroll
      for (int c = 0; c < 6; ++c) sh_part6[c][wv][lane] = acc[c];
    }
    __syncthreads();
    if (tid < 128) {
      int sub = tid >> 6, bb = tid & 63;
      int jh = bx * 2 + sub;
      float ac[3];
#pragma unroll
      for (int g = 0; g < 3; ++g) {
        float sgc = 0.f;
#pragma unroll
        for (int w8 = 0; w8 < 8; ++w8) sgc += sh_part6[g * 2 + sub][w8][bb];
        ac[g] = sgc;
      }
      const __half* g = gie + (size_t)t * G3 * 64;
      float gir = __half2float(g[(size_t)jh * 64 + bb]);
      float giz = __half2float(g[(size_t)(512 + jh) * 64 + bb]);
      float gin = __half2float(g[(size_t)(1024 + jh) * 64 + bb]);
      float ghr = out1[(size_t)(512 + jh) * 64 + bb];
      float ghz = out1[(size_t)(1024 + jh) * 64 + bb];
      float ghn = out1[(size_t)(1536 + jh) * 64 + bb];
      float r = 1.f / (1.f + expf(-(gir + ac[0] + ghr)));
      float z = 1.f / (1.f + expf(-(giz + ac[1] + ghz)));
      float nn = tanhf(gin + ac[2] + r * ghn);
      float hp = h32[(size_t)jh * 64 + bb];
      float hv = (1.f - z) * nn + z * hp;
      h32[(size_t)jh * 64 + bb] = hv;
      ((__half*)h2g)[((size_t)bx * 64 + bb) * 2 + sub] = __float2half(hv);
      out_h[((size_t)bb * L + t) * H_ + jh] = hv;
    }
    gg.sync();  // ---- sync3: h ready for next step ----
  }
}

// ---------------- launch ----------------

extern "C" void kernel_launch(void* const* d_in, const int* in_sizes, int n_in,
                              void* d_out, int out_size, void* d_ws, size_t ws_size,
                              hipStream_t stream) {
  const float* emb    = (const float*)d_in[0];
  const float* value  = (const float*)d_in[1];
  const float* vmask  = (const float*)d_in[2];
  const float* state  = (const float*)d_in[3];
  const float* Wq     = (const float*)d_in[4];
  const float* Wk     = (const float*)d_in[5];
  const float* b_attn = (const float*)d_in[6];
  const float* w_cov  = (const float*)d_in[7];
  const float* v_attn = (const float*)d_in[8];
  const float* W_ih   = (const float*)d_in[9];
  const float* W_hh   = (const float*)d_in[10];
  const float* b_ih   = (const float*)d_in[11];
  const float* b_hh   = (const float*)d_in[12];

  float* out = (float*)d_out;
  float* attn_out = out + (size_t)B * L * H_;

  __half* vk_h   = (__half*)d_ws;                         // B*N*H halfs
  __half* val_h  = vk_h + (size_t)B * N_ * H_;            // B*N*H halfs
  __half* gie_h  = val_h + (size_t)B * N_ * H_;           // L*G3*B halfs
  float* h32     = (float*)(gie_h + (size_t)L * G3 * B);  // H*B
  unsigned* h2g  = (unsigned*)(h32 + H_ * B);             // 16384
  float* cov     = (float*)(h2g + 16384);                 // B*N
  float* out1    = cov + (size_t)B * N_;                  // 2048*64
  float* scores  = out1 + (size_t)2048 * 64;              // B*N
  unsigned* ctx2 = (unsigned*)(scores + (size_t)B * N_);  // 16384
  unsigned* scnt = ctx2 + 16384;                          // 64

  k_init<<<64, 512, 0, stream>>>(state, h32, h2g, cov, scnt);
  k_cvt<<<16384, 256, 0, stream>>>(value, val_h);
  k_vk<<<dim3(8, 8, B), 256, 0, stream>>>(value, Wk, b_attn, vk_h);
  k_gie<<<dim3(24, 128), 256, 0, stream>>>(emb, W_ih, b_ih, gie_h);

  void* args[] = {(void*)&vk_h, (void*)&val_h, (void*)&gie_h, (void*)&Wq,
                  (void*)&W_hh, (void*)&W_ih,  (void*)&b_hh,  (void*)&w_cov,
                  (void*)&v_attn, (void*)&vmask, (void*)&cov, (void*)&h32,
                  (void*)&h2g, (void*)&out1, (void*)&scores, (void*)&ctx2,
                  (void*)&scnt, (void*)&out, (void*)&attn_out};
  hipLaunchCooperativeKernel((void*)k_step, dim3(256), dim3(512), args, 0,
                             stream);
}